// Round 27
// baseline (1990.279 us; speedup 1.0000x reference)
//
#include <hip/hip_runtime.h>

#define F1 62400
#define O1 800
#define O2N 100
#define TT 300
#define BB 2
#define NWRD 975        /* 64-bit f-words */
#define KSRM 77
#define KREF 11
#define M32 25          /* M-blocks of 32 o */
#define NPAD 640        /* n = b*320 + t */
#define NDIG 4          /* base-256 digits of rint(w1 * 2^31) — exact (R4-proven) */
#define KSPL 20         /* k-splits */
#define WPS 49          /* words per split (last split: 44) */
#define BSTRIDE ((size_t)NPAD * 4)

/* k_pre grid partition */
#define NB_K1 2438      /* ceil(2*975*5*64 / 256) */

typedef unsigned long long u64;
typedef int i32x4 __attribute__((ext_vector_type(4)));

/* chunk swizzle (T2, both-sides): bijective within each 16-chunk group */
#define CSWZ(c) ((c) ^ ((((c) >> 4) & 3) << 1))

/* ---- ws layout (bytes); NEED ~97 MB ---- */
#define OFF_CONST 0ull
#define OFF_Z1P  1024ull                          /* 20*800*640*8 = 81,920,000 */
#define OFF_S1T  (OFF_Z1P + 81920000ull)          /* 2*320*800*4 (t-major) */
#define OFF_XBW  (OFF_S1T + 2048000ull)           /* 975*640*8 (320-stride, pad 0) */
#define OFF_Z1F  (OFF_XBW + 4992000ull)
#define OFF_U1   (OFF_Z1F + 3840000ull)
#define OFF_U2   (OFF_U1 + 3840000ull)
#define NEED_SPARSE (OFF_U2 + 480000ull)          /* ~97.1 MB */

/* K0: SRM/REF kernels, fp64 rounded through fp32 (fallback path only). */
__global__ void k0_init(double* c) {
    int k = threadIdx.x;
    if (k < KSRM) {
        double v = ((double)k / 10.0) * exp(1.0 - (double)k / 10.0);
        c[k] = (double)(float)v;
    }
    if (k < KREF) {
        double v = -20.0 * (double)k * exp(1.0 - (double)k);
        c[80 + k] = (double)(float)v;
    }
}

/* K_PRE: bitmask build + constants. */
__global__ __launch_bounds__(256) void k_pre(const float* __restrict__ x,
                                             u64* __restrict__ xbw,
                                             double* __restrict__ cst) {
    int blk = blockIdx.x;
    if (blk < NB_K1) {
        const int NTG = 5;
        int gw = (blk * 256 + (int)threadIdx.x) >> 6;
        int lane = threadIdx.x & 63;
        if (gw >= BB * NWRD * NTG) return;
        int b  = gw / (NWRD * NTG);
        int r  = gw % (NWRD * NTG);
        int fw = r / NTG;
        int tg = r % NTG;
        int t = tg * 64 + lane;
        bool act = (t < TT);
        int tc = act ? t : 0;
        const float* xp = x + ((size_t)(b * F1 + (fw << 6))) * TT + tc;
        unsigned lo = 0, hi = 0;
        #pragma unroll
        for (int j = 0; j < 32; ++j)
            lo |= (xp[(size_t)j * TT] > 0.5f ? 1u : 0u) << j;
        #pragma unroll
        for (int j = 0; j < 32; ++j)
            hi |= (xp[(size_t)(j + 32) * TT] > 0.5f ? 1u : 0u) << j;
        u64 mval = act ? (((u64)hi << 32) | lo) : 0ull;
        xbw[(size_t)fw * NPAD + b * 320 + t] = mval;
    } else {
        int k = threadIdx.x;
        if (k < KSRM) {
            double v = ((double)k / 10.0) * exp(1.0 - (double)k / 10.0);
            cst[k] = (double)(float)v;
        }
        if (k < KREF) {
            double v = -20.0 * (double)k * exp(1.0 - (double)k);
            cst[80 + k] = (double)(float)v;
        }
    }
}

/* quantize 4 floats -> 4 digit-dwords. fp32 path exact (power-of-two scale). */
__device__ __forceinline__ void quant4(float4 f, unsigned dw[4]) {
    float ff[4] = {f.x, f.y, f.z, f.w};
    dw[0] = 0; dw[1] = 0; dw[2] = 0; dw[3] = 0;
    #pragma unroll
    for (int e = 0; e < 4; ++e) {
        int v  = (int)rintf(ff[e] * 2147483648.0f);
        int r0 = (v + 128) >> 8;
        int r1 = (r0 + 128) >> 8;
        int r2 = (r1 + 128) >> 8;
        dw[0] |= (unsigned)(v  & 0xFF) << (8 * e);
        dw[1] |= (unsigned)(r0 & 0xFF) << (8 * e);
        dw[2] |= (unsigned)(r1 & 0xFF) << (8 * e);
        dw[3] |= (unsigned)(r2 & 0xFF) << (8 * e);
    }
}

/* unpack 16 mask bits -> 16 i8 + 8 MFMAs (2 o-halves x 4 digits) */
#define K3_TILE(BV, TTI)                                                           \
    {                                                                              \
        i32x4 bf;                                                                  \
        _Pragma("unroll")                                                          \
        for (int i_ = 0; i_ < 4; ++i_)                                             \
            bf[i_] = (int)((((BV >> (4 * i_)) & 0xFu) * 0x00204081u) & 0x01010101u); \
        _Pragma("unroll")                                                          \
        for (int h_ = 0; h_ < 2; ++h_)                                             \
            _Pragma("unroll")                                                      \
            for (int d_ = 0; d_ < NDIG; ++d_)                                      \
                acc[TTI][h_][d_] = __builtin_amdgcn_mfma_i32_16x16x64_i8(          \
                    a[h_][d_], bf, acc[TTI][h_][d_], 0, 0, 0);                     \
    }

/* one pipeline iteration: compute step S from buf[S&1] + BU regs; quantize
   floats(S+1) (two float4s) into buf[(S+1)&1]; issue loads for S+2. */
#define K_ITER(S, FQ0, FQ1, FI0, FI1, BU0, BU1, BU2, BU3, BU4, BL0, BL1, BL2, BL3, BL4) \
    {                                                                              \
        int s_ = (S);                                                              \
        if (s_ < steps) {                                                          \
            int pf = s_ + 2; if (pf > steps - 1) pf = steps - 1;                   \
            FI0 = *(const float4*)(fbase + (size_t)pf * 64);                       \
            FI1 = *(const float4*)(fbase + (size_t)pf * 64 + 4);                   \
            int sn = s_ + 1; if (sn > steps - 1) sn = steps - 1;                   \
            const unsigned short* bpn = bp0 + (size_t)sn * BSTRIDE;                \
            BL0 = bpn[0]; BL1 = bpn[64]; BL2 = bpn[128]; BL3 = bpn[192]; BL4 = bpn[256]; \
            const char* lp = &Abuf[s_ & 1][0];                                     \
            i32x4 a[2][4];                                                         \
            _Pragma("unroll")                                                      \
            for (int h_ = 0; h_ < 2; ++h_)                                         \
                _Pragma("unroll")                                                  \
                for (int d_ = 0; d_ < NDIG; ++d_)                                  \
                    a[h_][d_] = *(const i32x4*)(lp + h_ * 4096 + d_ * 1024 + lofs); \
            K3_TILE(BU0, 0)                                                        \
            K3_TILE(BU1, 1)                                                        \
            K3_TILE(BU2, 2)                                                        \
            K3_TILE(BU3, 3)                                                        \
            K3_TILE(BU4, 4)                                                        \
            unsigned dq0[4], dq1[4];                                               \
            quant4(FQ0, dq0);                                                      \
            quant4(FQ1, dq1);                                                      \
            char* wb = &Abuf[(s_ + 1) & 1][0] + wofs;                              \
            _Pragma("unroll")                                                      \
            for (int d_ = 0; d_ < 4; ++d_) {                                       \
                *(unsigned*)(wb + d_ * 1024)     = dq0[d_];                        \
                *(unsigned*)(wb + d_ * 1024 + 4) = dq1[d_];                        \
            }                                                                      \
        }                                                                          \
        __syncthreads();                                                           \
    }

/* K3M2: exact i8 MFMA GEMM, M32 tile, fused fp32 quantization.
   256-thread blocks (4 waves), grid (25,20,2): finer residency quantum ->
   multiple blocks/CU so VALU-phase and MFMA-phase waves co-issue (m114). */
__global__ __launch_bounds__(256, 4) void k3m2(const float* __restrict__ w1,
                                               const u64* __restrict__ xbw,
                                               u64* __restrict__ z1p) {
    __shared__ __align__(16) char Abuf[2][8192];
    int m32 = blockIdx.x, ksl = blockIdx.y, nh = blockIdx.z;
    int tid = threadIdx.x;
    int l = tid & 63, wid = tid >> 6;          /* wid = n-slice 0..3 */
    int o  = tid >> 3;                         /* 0..31: my w1 row    */
    int kb = tid & 7;                          /* 8-k group: k = kb*8 */

    int wl0 = ksl * WPS;
    int wend = wl0 + WPS; if (wend > NWRD) wend = NWRD;
    int steps = wend - wl0;          /* 49 or 44 */

    i32x4 acc[5][2][NDIG];
    #pragma unroll
    for (int i = 0; i < 5; ++i)
        #pragma unroll
        for (int h = 0; h < 2; ++h)
            #pragma unroll
            for (int d = 0; d < NDIG; ++d) acc[i][h][d] = (i32x4){0, 0, 0, 0};

    const float* fbase = w1 + (size_t)(m32 * 32 + o) * F1 + (size_t)wl0 * 64 + kb * 8;
    const unsigned short* bp0 =
        (const unsigned short*)((const char*)xbw
            + ((size_t)wl0 * NPAD
               + (size_t)(nh * 320 + wid * 80 + (l & 15))) * 8
            + (l >> 4) * 2);
    const int lofs = CSWZ(l) * 16;
    const int wc = (kb >> 1) * 16 + (o & 15);
    const int wofs = (o >> 4) * 4096 + CSWZ(wc) * 16 + (kb & 1) * 8;

    float4 fA0, fA1, fB0, fB1, fC0, fC1;
    unsigned bA0, bA1, bA2, bA3, bA4;
    unsigned bB0, bB1, bB2, bB3, bB4;
    unsigned bC0, bC1, bC2, bC3, bC4;

    /* prologue: quantize step 0 into buf0; prefetch floats(1); B(0) */
    fA0 = *(const float4*)(fbase);
    fA1 = *(const float4*)(fbase + 4);
    {
        unsigned dq0[4], dq1[4];
        quant4(fA0, dq0);
        quant4(fA1, dq1);
        char* wb = &Abuf[0][0] + wofs;
        #pragma unroll
        for (int d = 0; d < 4; ++d) {
            *(unsigned*)(wb + d * 1024)     = dq0[d];
            *(unsigned*)(wb + d * 1024 + 4) = dq1[d];
        }
    }
    {
        size_t off1 = (steps > 1) ? 64 : 0;
        fB0 = *(const float4*)(fbase + off1);
        fB1 = *(const float4*)(fbase + off1 + 4);
    }
    bA0 = bp0[0]; bA1 = bp0[64]; bA2 = bp0[128]; bA3 = bp0[192]; bA4 = bp0[256];
    __syncthreads();

    int smax3 = ((steps + 2) / 3) * 3;
    #pragma unroll 1
    for (int sb = 0; sb < smax3; sb += 3) {
        K_ITER(sb,     fB0, fB1, fC0, fC1, bA0, bA1, bA2, bA3, bA4, bB0, bB1, bB2, bB3, bB4)
        K_ITER(sb + 1, fC0, fC1, fA0, fA1, bB0, bB1, bB2, bB3, bB4, bC0, bC1, bC2, bC3, bC4)
        K_ITER(sb + 2, fA0, fA1, fB0, fB1, bC0, bC1, bC2, bC3, bC4, bA0, bA1, bA2, bA3, bA4)
    }

    /* atomic-free epilogue: plain stores into this ksplit's partial plane */
    u64* zp = z1p + (size_t)ksl * O1 * NPAD;
    #pragma unroll
    for (int tt = 0; tt < 5; ++tt) {
        int n = nh * 320 + wid * 80 + tt * 16 + (l & 15);
        #pragma unroll
        for (int h = 0; h < 2; ++h) {
            #pragma unroll
            for (int r = 0; r < 4; ++r) {
                int oo = m32 * 32 + h * 16 + (l >> 4) * 4 + r;
                long long c = (long long)acc[tt][h][0][r]
                            + ((long long)acc[tt][h][1][r] << 8)
                            + ((long long)acc[tt][h][2][r] << 16)
                            + ((long long)acc[tt][h][3][r] << 24);
                zp[(size_t)oo * NPAD + n] = (u64)c;
            }
        }
    }
}

/* dense fallback GEMM1 (used only if ws too small) -> z1f fp64 */
__global__ __launch_bounds__(256) void k_dense_gemm1(const float* __restrict__ x,
                                                     const float* __restrict__ w1,
                                                     double* __restrict__ z1) {
    int lin = blockIdx.x;
    int ot = lin % 25; int tt = (lin / 25) % 5; int b = lin / 125;
    int t0 = tt * 64, o0 = ot * 32;
    __shared__ float xs[64][64];
    __shared__ float wsh[32][64];
    int ti = threadIdx.x & 63, og = threadIdx.x >> 6;
    double dacc[8] = {0, 0, 0, 0, 0, 0, 0, 0};
    for (int fc = 0; fc < F1; fc += 64) {
        __syncthreads();
        for (int e = threadIdx.x; e < 64 * 64; e += 256) {
            int r = e >> 6, c = e & 63;
            int t = t0 + c;
            xs[r][c] = (t < TT) ? x[((size_t)b * F1 + fc + r) * TT + t] : 0.0f;
        }
        for (int e = threadIdx.x; e < 32 * 64; e += 256) {
            int r = e >> 6, c = e & 63;
            wsh[r][c] = w1[(size_t)(o0 + r) * F1 + fc + c];
        }
        __syncthreads();
        float facc[8] = {0, 0, 0, 0, 0, 0, 0, 0};
        for (int ff = 0; ff < 64; ++ff) {
            float xv = xs[ff][ti];
            #pragma unroll
            for (int oo = 0; oo < 8; ++oo) facc[oo] += wsh[og * 8 + oo][ff] * xv;
        }
        #pragma unroll
        for (int oo = 0; oo < 8; ++oo) dacc[oo] += (double)facc[oo];
    }
    int t = t0 + ti;
    if (t < TT) {
        #pragma unroll
        for (int oo = 0; oo < 8; ++oo) {
            int o = o0 + og * 8 + oo;
            z1[((size_t)(b * O1 + o)) * TT + t] = dacc[oo];
        }
    }
}

/* K_CONV1: exact i64 partial-sum (20 planes) + scale + psp conv. */
__global__ __launch_bounds__(320) void k_conv1(const u64* __restrict__ z1p,
                                               const double* __restrict__ z1f,
                                               double* __restrict__ u1,
                                               const double* __restrict__ cst,
                                               int mode) {
    __shared__ double zs[TT];
    __shared__ double ck[KSRM];
    int row = blockIdx.x;                 /* b*800 + o */
    int b = row / O1, o = row % O1;
    int t = threadIdx.x;
    if (t < KSRM) ck[t] = cst[t];
    if (t < TT) {
        double z;
        if (mode == 0) {
            long long c = 0;
            size_t base = (size_t)o * NPAD + b * 320 + t;
            #pragma unroll
            for (int g = 0; g < KSPL; ++g)
                c += (long long)z1p[(size_t)g * O1 * NPAD + base];
            z = (double)c * 4.656612873077393e-10;          /* 2^-31 */
        } else {
            z = z1f[(size_t)row * TT + t];
        }
        zs[t] = z;
    }
    __syncthreads();
    if (t < TT) {
        int kmax = t < (KSRM - 1) ? t : (KSRM - 1);
        double acc = 0.0;
        for (int k = 0; k <= kmax; ++k) acc += ck[k] * zs[t - k];
        u1[(size_t)row * TT + t] = acc;
    }
}

/* K_SCAN: thread-per-row spike scan, 30-deep register load pipeline.
   tmode=1 (layer1): t-major output; tmode=0 (layer2): row-major. */
__global__ __launch_bounds__(64) void k_scan(const double* __restrict__ u,
                                             float* __restrict__ s,
                                             const double* __restrict__ cst,
                                             int nrows, int tmode) {
    int row = blockIdx.x * 64 + threadIdx.x;
    if (row >= nrows) return;
    double rk1 = cst[81], rk2 = cst[82], rk3 = cst[83], rk4 = cst[84];
    double rk5 = cst[85], rk6 = cst[86], rk7 = cst[87], rk8 = cst[88];
    double rk9 = cst[89], rk10 = cst[90];
    const double* ur = u + (size_t)row * TT;
    float* sbase;
    size_t sstep;
    if (tmode) {
        int b = (row >= O1) ? 1 : 0;
        int f = row - b * O1;
        sbase = s + (size_t)(b * 320) * O1 + f;
        sstep = O1;
    } else {
        sbase = s + (size_t)row * TT;
        sstep = 1;
    }
    double buf[30];
    #pragma unroll
    for (int j = 0; j < 30; ++j) buf[j] = ur[j];
    unsigned h = 0;
    #pragma unroll 1
    for (int tb = 0; tb < TT; tb += 30) {
        double nxt[30];
        #pragma unroll
        for (int j = 0; j < 30; ++j) {
            int tn = tb + 30 + j; if (tn > TT - 1) tn = TT - 1;
            nxt[j] = ur[tn];
        }
        #pragma unroll
        for (int j = 0; j < 30; ++j) {
            double a  = ((h & 1u)   ? rk1 : 0.0) + ((h & 2u)   ? rk2  : 0.0);
            double b2 = ((h & 4u)   ? rk3 : 0.0) + ((h & 8u)   ? rk4  : 0.0);
            double c2 = ((h & 16u)  ? rk5 : 0.0) + ((h & 32u)  ? rk6  : 0.0);
            double d2 = ((h & 64u)  ? rk7 : 0.0) + ((h & 128u) ? rk8  : 0.0);
            double e2 = ((h & 256u) ? rk9 : 0.0) + ((h & 512u) ? rk10 : 0.0);
            double ueff = buf[j] + (((a + b2) + (c2 + d2)) + e2);
            unsigned sp = (ueff >= 10.0) ? 1u : 0u;
            sbase[(size_t)(tb + j) * sstep] = (float)sp;
            h = (h << 1) | sp;
        }
        #pragma unroll
        for (int j = 0; j < 30; ++j) buf[j] = nxt[j];
    }
}

/* K_GEMM2C: fused GEMM2 + psp conv; t-major s1t -> contiguous float4 reads. */
__global__ __launch_bounds__(320) void k_gemm2c(const float* __restrict__ s1t,
                                                const float* __restrict__ w2,
                                                double* __restrict__ u2,
                                                const double* __restrict__ cst) {
    __shared__ float wsm[O1];
    __shared__ double zs[TT];
    __shared__ double ck[KSRM];
    int bo = blockIdx.x;
    int b = bo / O2N, o2 = bo % O2N;
    int t = threadIdx.x;
    if (t < KSRM) ck[t] = cst[t];
    for (int f = t; f < O1; f += 320) wsm[f] = w2[(size_t)o2 * O1 + f];
    __syncthreads();
    if (t < TT) {
        const float4* sp = (const float4*)(s1t + (size_t)(b * 320 + t) * O1);
        double acc = 0.0;
        #pragma unroll 4
        for (int ff = 0; ff < O1 / 4; ++ff) {
            float4 v = sp[ff];
            acc += (double)(wsm[4 * ff]     * v.x);
            acc += (double)(wsm[4 * ff + 1] * v.y);
            acc += (double)(wsm[4 * ff + 2] * v.z);
            acc += (double)(wsm[4 * ff + 3] * v.w);
        }
        zs[t] = acc;
    }
    __syncthreads();
    if (t < TT) {
        int kmax = t < (KSRM - 1) ? t : (KSRM - 1);
        double acc = 0.0;
        for (int k = 0; k <= kmax; ++k) acc += ck[k] * zs[t - k];
        u2[(size_t)bo * TT + t] = acc;
    }
}

extern "C" void kernel_launch(void* const* d_in, const int* in_sizes, int n_in,
                              void* d_out, int out_size, void* d_ws, size_t ws_size,
                              hipStream_t stream) {
    const float* x  = (const float*)d_in[0];
    const float* w1 = (const float*)d_in[1];
    const float* w2 = (const float*)d_in[2];
    float* out = (float*)d_out;
    char* ws = (char*)d_ws;

    double* cst = (double*)(ws + OFF_CONST);
    u64*    z1p = (u64*)   (ws + OFF_Z1P);
    float*  s1t = (float*) (ws + OFF_S1T);
    u64*    xbw = (u64*)   (ws + OFF_XBW);
    double* z1f = (double*)(ws + OFF_Z1F);
    double* u1  = (double*)(ws + OFF_U1);
    double* u2  = (double*)(ws + OFF_U2);

    int mode;
    if (ws_size >= NEED_SPARSE) {
        mode = 0;
        k_pre<<<NB_K1 + 1, 256, 0, stream>>>(x, xbw, cst);
        k3m2<<<dim3(M32, KSPL, 2), 256, 0, stream>>>(w1, xbw, z1p);
    } else {
        mode = 1;
        k0_init<<<1, 128, 0, stream>>>(cst);
        k_dense_gemm1<<<250, 256, 0, stream>>>(x, w1, z1f);
    }

    k_conv1<<<BB * O1, 320, 0, stream>>>(z1p, z1f, u1, cst, mode);
    k_scan<<<(BB * O1 + 63) / 64, 64, 0, stream>>>(u1, s1t, cst, BB * O1, 1);
    k_gemm2c<<<BB * O2N, 320, 0, stream>>>(s1t, w2, u2, cst);
    k_scan<<<(BB * O2N + 63) / 64, 64, 0, stream>>>(u2, out, cst, BB * O2N, 0);
    (void)in_sizes; (void)n_in; (void)out_size;
}

// Round 28
// 258.209 us; speedup vs baseline: 7.7080x; 7.7080x over previous
//
#include <hip/hip_runtime.h>

#define F1 62400
#define O1 800
#define O2N 100
#define TT 300
#define BB 2
#define NWRD 975        /* 64-bit f-words */
#define KSRM 77
#define KREF 11
#define M32 25          /* M-blocks of 32 o */
#define NPAD 640        /* n = b*320 + t */
#define NDIG 4          /* base-256 digits of rint(w1 * 2^31) — exact (R4-proven) */
#define KSPL 20         /* k-splits */
#define WPS 49          /* words per split (last split: 44) */
#define BSTRIDE ((size_t)NPAD * 4)

/* k_pre grid partition */
#define NB_K1 2438      /* ceil(2*975*5*64 / 256) */

typedef unsigned long long u64;
typedef int i32x4 __attribute__((ext_vector_type(4)));

/* chunk swizzle (T2, both-sides): bijective within each 16-chunk group */
#define CSWZ(c) ((c) ^ ((((c) >> 4) & 3) << 1))

/* ---- ws layout (bytes); NEED ~97 MB ---- */
#define OFF_CONST 0ull
#define OFF_Z1P  1024ull                          /* 20*800*640*8 = 81,920,000 */
#define OFF_S1T  (OFF_Z1P + 81920000ull)          /* 2*320*800*4 (t-major) */
#define OFF_XBW  (OFF_S1T + 2048000ull)           /* 975*640*8 (320-stride, pad 0) */
#define OFF_Z1F  (OFF_XBW + 4992000ull)
#define OFF_U1   (OFF_Z1F + 3840000ull)
#define OFF_U2   (OFF_U1 + 3840000ull)
#define NEED_SPARSE (OFF_U2 + 480000ull)          /* ~97.1 MB */

/* K0: SRM/REF kernels, fp64 rounded through fp32 (fallback path only). */
__global__ void k0_init(double* c) {
    int k = threadIdx.x;
    if (k < KSRM) {
        double v = ((double)k / 10.0) * exp(1.0 - (double)k / 10.0);
        c[k] = (double)(float)v;
    }
    if (k < KREF) {
        double v = -20.0 * (double)k * exp(1.0 - (double)k);
        c[80 + k] = (double)(float)v;
    }
}

/* K_PRE: bitmask build + constants. */
__global__ __launch_bounds__(256) void k_pre(const float* __restrict__ x,
                                             u64* __restrict__ xbw,
                                             double* __restrict__ cst) {
    int blk = blockIdx.x;
    if (blk < NB_K1) {
        const int NTG = 5;
        int gw = (blk * 256 + (int)threadIdx.x) >> 6;
        int lane = threadIdx.x & 63;
        if (gw >= BB * NWRD * NTG) return;
        int b  = gw / (NWRD * NTG);
        int r  = gw % (NWRD * NTG);
        int fw = r / NTG;
        int tg = r % NTG;
        int t = tg * 64 + lane;
        bool act = (t < TT);
        int tc = act ? t : 0;
        const float* xp = x + ((size_t)(b * F1 + (fw << 6))) * TT + tc;
        unsigned lo = 0, hi = 0;
        #pragma unroll
        for (int j = 0; j < 32; ++j)
            lo |= (xp[(size_t)j * TT] > 0.5f ? 1u : 0u) << j;
        #pragma unroll
        for (int j = 0; j < 32; ++j)
            hi |= (xp[(size_t)(j + 32) * TT] > 0.5f ? 1u : 0u) << j;
        u64 mval = act ? (((u64)hi << 32) | lo) : 0ull;
        xbw[(size_t)fw * NPAD + b * 320 + t] = mval;
    } else {
        int k = threadIdx.x;
        if (k < KSRM) {
            double v = ((double)k / 10.0) * exp(1.0 - (double)k / 10.0);
            cst[k] = (double)(float)v;
        }
        if (k < KREF) {
            double v = -20.0 * (double)k * exp(1.0 - (double)k);
            cst[80 + k] = (double)(float)v;
        }
    }
}

/* quantize 4 floats -> 4 digit-dwords. fp32 path exact (power-of-two scale). */
__device__ __forceinline__ void quant4(float4 f, unsigned dw[4]) {
    float ff[4] = {f.x, f.y, f.z, f.w};
    dw[0] = 0; dw[1] = 0; dw[2] = 0; dw[3] = 0;
    #pragma unroll
    for (int e = 0; e < 4; ++e) {
        int v  = (int)rintf(ff[e] * 2147483648.0f);
        int r0 = (v + 128) >> 8;
        int r1 = (r0 + 128) >> 8;
        int r2 = (r1 + 128) >> 8;
        dw[0] |= (unsigned)(v  & 0xFF) << (8 * e);
        dw[1] |= (unsigned)(r0 & 0xFF) << (8 * e);
        dw[2] |= (unsigned)(r1 & 0xFF) << (8 * e);
        dw[3] |= (unsigned)(r2 & 0xFF) << (8 * e);
    }
}

/* unpack 16 mask bits -> 16 i8 + 8 MFMAs (2 o-halves x 4 digits) */
#define K3_TILE(BV, TTI)                                                           \
    {                                                                              \
        i32x4 bf;                                                                  \
        _Pragma("unroll")                                                          \
        for (int i_ = 0; i_ < 4; ++i_)                                             \
            bf[i_] = (int)((((BV >> (4 * i_)) & 0xFu) * 0x00204081u) & 0x01010101u); \
        _Pragma("unroll")                                                          \
        for (int h_ = 0; h_ < 2; ++h_)                                             \
            _Pragma("unroll")                                                      \
            for (int d_ = 0; d_ < NDIG; ++d_)                                      \
                acc[TTI][h_][d_] = __builtin_amdgcn_mfma_i32_16x16x64_i8(          \
                    a[h_][d_], bf, acc[TTI][h_][d_], 0, 0, 0);                     \
    }

#define K_ITER(S, FQ, FI, BU0, BU1, BU2, BU3, BU4, BL0, BL1, BL2, BL3, BL4)        \
    {                                                                              \
        int s_ = (S);                                                              \
        if (s_ < steps) {                                                          \
            int pf = s_ + 2; if (pf > steps - 1) pf = steps - 1;                   \
            FI = *(const float4*)(fbase + (size_t)pf * 64);                        \
            int sn = s_ + 1; if (sn > steps - 1) sn = steps - 1;                   \
            const unsigned short* bpn = bp0 + (size_t)sn * BSTRIDE;                \
            BL0 = bpn[0]; BL1 = bpn[64]; BL2 = bpn[128]; BL3 = bpn[192]; BL4 = bpn[256]; \
            const char* lp = &Abuf[s_ & 1][0];                                     \
            i32x4 a[2][4];                                                         \
            _Pragma("unroll")                                                      \
            for (int h_ = 0; h_ < 2; ++h_)                                         \
                _Pragma("unroll")                                                  \
                for (int d_ = 0; d_ < NDIG; ++d_)                                  \
                    a[h_][d_] = *(const i32x4*)(lp + h_ * 4096 + d_ * 1024 + lofs); \
            K3_TILE(BU0, 0)                                                        \
            K3_TILE(BU1, 1)                                                        \
            K3_TILE(BU2, 2)                                                        \
            K3_TILE(BU3, 3)                                                        \
            K3_TILE(BU4, 4)                                                        \
            unsigned dwq[4];                                                       \
            quant4(FQ, dwq);                                                       \
            char* wb = &Abuf[(s_ + 1) & 1][0] + wofs;                              \
            *(unsigned*)(wb)        = dwq[0];                                      \
            *(unsigned*)(wb + 1024) = dwq[1];                                      \
            *(unsigned*)(wb + 2048) = dwq[2];                                      \
            *(unsigned*)(wb + 3072) = dwq[3];                                      \
        }                                                                          \
        __syncthreads();                                                           \
    }

/* K3M2: exact i8 MFMA GEMM, M32 tile, fused fp32 quantization (R26-proven). */
__global__ __launch_bounds__(512, 2) void k3m2(const float* __restrict__ w1,
                                               const u64* __restrict__ xbw,
                                               u64* __restrict__ z1p) {
    __shared__ __align__(16) char Abuf[2][8192];
    int m32 = blockIdx.x, ksl = blockIdx.y;
    int tid = threadIdx.x;
    int l = tid & 63, wid = tid >> 6;
    int o  = tid >> 4;
    int kq = tid & 15;

    int wl0 = ksl * WPS;
    int wend = wl0 + WPS; if (wend > NWRD) wend = NWRD;
    int steps = wend - wl0;          /* 49 or 44 */

    i32x4 acc[5][2][NDIG];
    #pragma unroll
    for (int i = 0; i < 5; ++i)
        #pragma unroll
        for (int h = 0; h < 2; ++h)
            #pragma unroll
            for (int d = 0; d < NDIG; ++d) acc[i][h][d] = (i32x4){0, 0, 0, 0};

    const float* fbase = w1 + (size_t)(m32 * 32 + o) * F1 + (size_t)wl0 * 64 + kq * 4;
    const unsigned short* bp0 =
        (const unsigned short*)((const char*)xbw
            + ((size_t)wl0 * NPAD
               + (size_t)(wid * 80 + (l & 15))) * 8
            + (l >> 4) * 2);
    const int lofs = CSWZ(l) * 16;
    const int wc = (kq >> 2) * 16 + (o & 15);
    const int wofs = (o >> 4) * 4096 + CSWZ(wc) * 16 + (kq & 3) * 4;

    float4 fA, fB, fC;
    unsigned bA0, bA1, bA2, bA3, bA4;
    unsigned bB0, bB1, bB2, bB3, bB4;
    unsigned bC0, bC1, bC2, bC3, bC4;

    fA = *(const float4*)(fbase);
    {
        unsigned dwq[4];
        quant4(fA, dwq);
        char* wb = &Abuf[0][0] + wofs;
        *(unsigned*)(wb)        = dwq[0];
        *(unsigned*)(wb + 1024) = dwq[1];
        *(unsigned*)(wb + 2048) = dwq[2];
        *(unsigned*)(wb + 3072) = dwq[3];
    }
    fB = *(const float4*)(fbase + ((steps > 1) ? 64 : 0));
    bA0 = bp0[0]; bA1 = bp0[64]; bA2 = bp0[128]; bA3 = bp0[192]; bA4 = bp0[256];
    __syncthreads();

    int smax3 = ((steps + 2) / 3) * 3;
    #pragma unroll 1
    for (int sb = 0; sb < smax3; sb += 3) {
        K_ITER(sb,     fB, fC, bA0, bA1, bA2, bA3, bA4, bB0, bB1, bB2, bB3, bB4)
        K_ITER(sb + 1, fC, fA, bB0, bB1, bB2, bB3, bB4, bC0, bC1, bC2, bC3, bC4)
        K_ITER(sb + 2, fA, fB, bC0, bC1, bC2, bC3, bC4, bA0, bA1, bA2, bA3, bA4)
    }

    u64* zp = z1p + (size_t)ksl * O1 * NPAD;
    #pragma unroll
    for (int tt = 0; tt < 5; ++tt) {
        int n = wid * 80 + tt * 16 + (l & 15);
        #pragma unroll
        for (int h = 0; h < 2; ++h) {
            #pragma unroll
            for (int r = 0; r < 4; ++r) {
                int oo = m32 * 32 + h * 16 + (l >> 4) * 4 + r;
                long long c = (long long)acc[tt][h][0][r]
                            + ((long long)acc[tt][h][1][r] << 8)
                            + ((long long)acc[tt][h][2][r] << 16)
                            + ((long long)acc[tt][h][3][r] << 24);
                zp[(size_t)oo * NPAD + n] = (u64)c;
            }
        }
    }
}

/* dense fallback GEMM1 (used only if ws too small) -> z1f fp64 */
__global__ __launch_bounds__(256) void k_dense_gemm1(const float* __restrict__ x,
                                                     const float* __restrict__ w1,
                                                     double* __restrict__ z1) {
    int lin = blockIdx.x;
    int ot = lin % 25; int tt = (lin / 25) % 5; int b = lin / 125;
    int t0 = tt * 64, o0 = ot * 32;
    __shared__ float xs[64][64];
    __shared__ float wsh[32][64];
    int ti = threadIdx.x & 63, og = threadIdx.x >> 6;
    double dacc[8] = {0, 0, 0, 0, 0, 0, 0, 0};
    for (int fc = 0; fc < F1; fc += 64) {
        __syncthreads();
        for (int e = threadIdx.x; e < 64 * 64; e += 256) {
            int r = e >> 6, c = e & 63;
            int t = t0 + c;
            xs[r][c] = (t < TT) ? x[((size_t)b * F1 + fc + r) * TT + t] : 0.0f;
        }
        for (int e = threadIdx.x; e < 32 * 64; e += 256) {
            int r = e >> 6, c = e & 63;
            wsh[r][c] = w1[(size_t)(o0 + r) * F1 + fc + c];
        }
        __syncthreads();
        float facc[8] = {0, 0, 0, 0, 0, 0, 0, 0};
        for (int ff = 0; ff < 64; ++ff) {
            float xv = xs[ff][ti];
            #pragma unroll
            for (int oo = 0; oo < 8; ++oo) facc[oo] += wsh[og * 8 + oo][ff] * xv;
        }
        #pragma unroll
        for (int oo = 0; oo < 8; ++oo) dacc[oo] += (double)facc[oo];
    }
    int t = t0 + ti;
    if (t < TT) {
        #pragma unroll
        for (int oo = 0; oo < 8; ++oo) {
            int o = o0 + og * 8 + oo;
            z1[((size_t)(b * O1 + o)) * TT + t] = dacc[oo];
        }
    }
}

/* K_CONV1: exact i64 partial-sum (20 planes) + scale + psp conv. */
__global__ __launch_bounds__(320) void k_conv1(const u64* __restrict__ z1p,
                                               const double* __restrict__ z1f,
                                               double* __restrict__ u1,
                                               const double* __restrict__ cst,
                                               int mode) {
    __shared__ double zs[TT];
    __shared__ double ck[KSRM];
    int row = blockIdx.x;                 /* b*800 + o */
    int b = row / O1, o = row % O1;
    int t = threadIdx.x;
    if (t < KSRM) ck[t] = cst[t];
    if (t < TT) {
        double z;
        if (mode == 0) {
            long long c = 0;
            size_t base = (size_t)o * NPAD + b * 320 + t;
            #pragma unroll
            for (int g = 0; g < KSPL; ++g)
                c += (long long)z1p[(size_t)g * O1 * NPAD + base];
            z = (double)c * 4.656612873077393e-10;          /* 2^-31 */
        } else {
            z = z1f[(size_t)row * TT + t];
        }
        zs[t] = z;
    }
    __syncthreads();
    if (t < TT) {
        int kmax = t < (KSRM - 1) ? t : (KSRM - 1);
        double acc = 0.0;
        for (int k = 0; k <= kmax; ++k) acc += ck[k] * zs[t - k];
        u1[(size_t)row * TT + t] = acc;
    }
}

/* K_SCAN: thread-per-row spike scan, 30-deep register load pipeline.
   tmode=1 (layer1): t-major output; tmode=0 (layer2): row-major. */
__global__ __launch_bounds__(64) void k_scan(const double* __restrict__ u,
                                             float* __restrict__ s,
                                             const double* __restrict__ cst,
                                             int nrows, int tmode) {
    int row = blockIdx.x * 64 + threadIdx.x;
    if (row >= nrows) return;
    double rk1 = cst[81], rk2 = cst[82], rk3 = cst[83], rk4 = cst[84];
    double rk5 = cst[85], rk6 = cst[86], rk7 = cst[87], rk8 = cst[88];
    double rk9 = cst[89], rk10 = cst[90];
    const double* ur = u + (size_t)row * TT;
    float* sbase;
    size_t sstep;
    if (tmode) {
        int b = (row >= O1) ? 1 : 0;
        int f = row - b * O1;
        sbase = s + (size_t)(b * 320) * O1 + f;
        sstep = O1;
    } else {
        sbase = s + (size_t)row * TT;
        sstep = 1;
    }
    double buf[30];
    #pragma unroll
    for (int j = 0; j < 30; ++j) buf[j] = ur[j];
    unsigned h = 0;
    #pragma unroll 1
    for (int tb = 0; tb < TT; tb += 30) {
        double nxt[30];
        #pragma unroll
        for (int j = 0; j < 30; ++j) {
            int tn = tb + 30 + j; if (tn > TT - 1) tn = TT - 1;
            nxt[j] = ur[tn];
        }
        #pragma unroll
        for (int j = 0; j < 30; ++j) {
            double a  = ((h & 1u)   ? rk1 : 0.0) + ((h & 2u)   ? rk2  : 0.0);
            double b2 = ((h & 4u)   ? rk3 : 0.0) + ((h & 8u)   ? rk4  : 0.0);
            double c2 = ((h & 16u)  ? rk5 : 0.0) + ((h & 32u)  ? rk6  : 0.0);
            double d2 = ((h & 64u)  ? rk7 : 0.0) + ((h & 128u) ? rk8  : 0.0);
            double e2 = ((h & 256u) ? rk9 : 0.0) + ((h & 512u) ? rk10 : 0.0);
            double ueff = buf[j] + (((a + b2) + (c2 + d2)) + e2);
            unsigned sp = (ueff >= 10.0) ? 1u : 0u;
            sbase[(size_t)(tb + j) * sstep] = (float)sp;
            h = (h << 1) | sp;
        }
        #pragma unroll
        for (int j = 0; j < 30; ++j) buf[j] = nxt[j];
    }
}

/* K_GEMM2C: fused GEMM2 + psp conv; t-major s1t -> contiguous float4 reads. */
__global__ __launch_bounds__(320) void k_gemm2c(const float* __restrict__ s1t,
                                                const float* __restrict__ w2,
                                                double* __restrict__ u2,
                                                const double* __restrict__ cst) {
    __shared__ float wsm[O1];
    __shared__ double zs[TT];
    __shared__ double ck[KSRM];
    int bo = blockIdx.x;
    int b = bo / O2N, o2 = bo % O2N;
    int t = threadIdx.x;
    if (t < KSRM) ck[t] = cst[t];
    for (int f = t; f < O1; f += 320) wsm[f] = w2[(size_t)o2 * O1 + f];
    __syncthreads();
    if (t < TT) {
        const float4* sp = (const float4*)(s1t + (size_t)(b * 320 + t) * O1);
        double acc = 0.0;
        #pragma unroll 4
        for (int ff = 0; ff < O1 / 4; ++ff) {
            float4 v = sp[ff];
            acc += (double)(wsm[4 * ff]     * v.x);
            acc += (double)(wsm[4 * ff + 1] * v.y);
            acc += (double)(wsm[4 * ff + 2] * v.z);
            acc += (double)(wsm[4 * ff + 3] * v.w);
        }
        zs[t] = acc;
    }
    __syncthreads();
    if (t < TT) {
        int kmax = t < (KSRM - 1) ? t : (KSRM - 1);
        double acc = 0.0;
        for (int k = 0; k <= kmax; ++k) acc += ck[k] * zs[t - k];
        u2[(size_t)bo * TT + t] = acc;
    }
}

extern "C" void kernel_launch(void* const* d_in, const int* in_sizes, int n_in,
                              void* d_out, int out_size, void* d_ws, size_t ws_size,
                              hipStream_t stream) {
    const float* x  = (const float*)d_in[0];
    const float* w1 = (const float*)d_in[1];
    const float* w2 = (const float*)d_in[2];
    float* out = (float*)d_out;
    char* ws = (char*)d_ws;

    double* cst = (double*)(ws + OFF_CONST);
    u64*    z1p = (u64*)   (ws + OFF_Z1P);
    float*  s1t = (float*) (ws + OFF_S1T);
    u64*    xbw = (u64*)   (ws + OFF_XBW);
    double* z1f = (double*)(ws + OFF_Z1F);
    double* u1  = (double*)(ws + OFF_U1);
    double* u2  = (double*)(ws + OFF_U2);

    int mode;
    if (ws_size >= NEED_SPARSE) {
        mode = 0;
        k_pre<<<NB_K1 + 1, 256, 0, stream>>>(x, xbw, cst);
        k3m2<<<dim3(M32, KSPL), 512, 0, stream>>>(w1, xbw, z1p);
    } else {
        mode = 1;
        k0_init<<<1, 128, 0, stream>>>(cst);
        k_dense_gemm1<<<250, 256, 0, stream>>>(x, w1, z1f);
    }

    k_conv1<<<BB * O1, 320, 0, stream>>>(z1p, z1f, u1, cst, mode);
    k_scan<<<(BB * O1 + 63) / 64, 64, 0, stream>>>(u1, s1t, cst, BB * O1, 1);
    k_gemm2c<<<BB * O2N, 320, 0, stream>>>(s1t, w2, u2, cst);
    k_scan<<<(BB * O2N + 63) / 64, 64, 0, stream>>>(u2, out, cst, BB * O2N, 0);
    (void)in_sizes; (void)n_in; (void)out_size;
}